// Round 11
// baseline (98915.417 us; speedup 1.0000x reference)
//
#include <hip/hip_runtime.h>
#include <hip/hip_bf16.h>
#include <hip/hip_fp16.h>
#include <stdint.h>

constexpr int kT = 512;

// d_ws byte offsets
constexpr uint32_t WHP_OFF  = 0u;        // [64][512][8] fp16 : Wh[h][kb*8+e]
constexpr uint32_t WRSP_OFF = 524288u;   // [32][512][8] fp16 : Wr+Wr' summed
constexpr uint32_t WSP_OFF  = 786432u;   // [64][128][8] fp16 : Ws[o][kb*8+e]
constexpr uint32_t WEP_OFF  = 917504u;   // [32][512][8] bf16 : We[h][kb*8+e]
constexpr uint32_t BIAS_OFF = 1179648u;  // [512] f32
constexpr uint32_t X_OFF    = 1181696u;  // fast: [2][64][4][128] u32 (same-XCD L2)
constexpr uint32_t XS_OFF   = 1443840u;  // slow: same layout (agent/IF$ fallback)

// d_out element offsets (fp32)
constexpr uint32_t OUT_HL = 16777216u;
constexpr uint32_t OUT_SR = 16809984u;

static __device__ __forceinline__ float bitsf(uint32_t u) {
  union { uint32_t u; float f; } c; c.u = u; return c.f;
}

typedef _Float16 h2_t __attribute__((ext_vector_type(2)));

static __device__ __forceinline__ float dot2acc(uint32_t w, uint32_t h, float acc) {
#if __has_builtin(__builtin_amdgcn_fdot2)
  return __builtin_amdgcn_fdot2(__builtin_bit_cast(h2_t, w),
                                __builtin_bit_cast(h2_t, h), acc, false);
#else
  h2_t wv = __builtin_bit_cast(h2_t, w), hv = __builtin_bit_cast(h2_t, h);
  return acc + (float)wv.x * (float)hv.x + (float)wv.y * (float)hv.y;
#endif
}

static __device__ __forceinline__ float dot8h(uint4 w, uint4 h, float acc) {
  acc = dot2acc(w.x, h.x, acc);
  acc = dot2acc(w.y, h.y, acc);
  acc = dot2acc(w.z, h.z, acc);
  acc = dot2acc(w.w, h.w, acc);
  return acc;
}

// sc0 (agent-coherent-at-L1) load/store: bypass L1, service at this XCD's L2
static __device__ __forceinline__ uint32_t load_l2(const uint32_t* p) {
  uint32_t v;
  asm volatile("global_load_dword %0, %1, off sc0\n\ts_waitcnt vmcnt(0)"
               : "=v"(v) : "v"(p));
  return v;
}
static __device__ __forceinline__ void store_l2(uint32_t* p, uint32_t v) {
  asm volatile("global_store_dword %0, %1, off sc0" :: "v"(p), "v"(v) : "memory");
}

// opaque keep-alive: blocks load rematerialization of register-resident weights
#define KEEP4(v) asm volatile("" : "+v"((v).x), "+v"((v).y), "+v"((v).z), "+v"((v).w))

// ---------------- kernel 0: pack weights + fold biases ----------------
__global__ __launch_bounds__(256) void pack_kernel(
    const float* __restrict__ Wh, const float* __restrict__ Wr,
    const float* __restrict__ Ws, const float* __restrict__ We,
    const float* __restrict__ be, const float* __restrict__ bh,
    const float* __restrict__ br, char* __restrict__ ws)
{
  uint32_t g = blockIdx.x * 256u + threadIdx.x;
  __half* whp  = (__half*)(ws + WHP_OFF);
  __half* wrsp = (__half*)(ws + WRSP_OFF);
  __half* wsp  = (__half*)(ws + WSP_OFF);
  __hip_bfloat16* wep = (__hip_bfloat16*)(ws + WEP_OFF);
  float* bias = (float*)(ws + BIAS_OFF);

  if (g < 262144u) {
    uint32_t e = g & 7u, h = (g >> 3) & 511u, kb = g >> 12;
    whp[g] = __float2half(Wh[h * 512u + kb * 8u + e]);
  }
  if (g < 131072u) {
    uint32_t e = g & 7u, h = (g >> 3) & 511u, jb = g >> 12;
    wrsp[g] = __float2half(Wr[h * 256u + jb * 8u + e] +
                           Wr[(512u + h) * 256u + jb * 8u + e]);
  }
  if (g < 65536u) {
    uint32_t e = g & 7u, o = (g >> 3) & 127u, kb = g >> 10;
    wsp[g] = __float2half(Ws[o * 512u + kb * 8u + e]);
  }
  if (g < 131072u) {
    uint32_t e = g & 7u, h = (g >> 3) & 511u, kb = g >> 12;
    wep[g] = __float2bfloat16(We[h * 256u + kb * 8u + e]);
  }
  if (g < 512u) bias[g] = be[g] + bh[g] + br[g] + br[512u + g];
}

// ---------------- kernel 1: E = emb @ We.T + biases -> d_out output region --------
__global__ __launch_bounds__(256) void embed_kernel(
    const float* __restrict__ embs, const char* __restrict__ ws,
    float* __restrict__ out)
{
  __shared__ __align__(16) float embL[16 * 256];
  const uint32_t tid = threadIdx.x;
  const uint32_t r0 = blockIdx.x * 16u;
  #pragma unroll
  for (int i = 0; i < 16; i++) embL[tid + i * 256] = embs[r0 * 256u + tid + i * 256u];
  __syncthreads();

  const uint4* wep = (const uint4*)(ws + WEP_OFF);
  const float* bias = (const float*)(ws + BIAS_OFF);

  for (int hb = 0; hb < 2; hb++) {
    uint32_t h = hb * 256u + tid;
    float acc[16];
    #pragma unroll
    for (int r = 0; r < 16; r++) acc[r] = 0.f;
    for (int kb = 0; kb < 32; kb++) {
      uint4 v = wep[kb * 512u + h];
      float w0 = bitsf(v.x << 16), w1 = bitsf(v.x & 0xffff0000u);
      float w2 = bitsf(v.y << 16), w3 = bitsf(v.y & 0xffff0000u);
      float w4 = bitsf(v.z << 16), w5 = bitsf(v.z & 0xffff0000u);
      float w6 = bitsf(v.w << 16), w7 = bitsf(v.w & 0xffff0000u);
      #pragma unroll
      for (int r = 0; r < 16; r++) {
        const float4* e4 = (const float4*)&embL[r * 256 + kb * 8];
        float4 a = e4[0], c = e4[1];
        acc[r] += w0 * a.x + w1 * a.y + w2 * a.z + w3 * a.w
                + w4 * c.x + w5 * c.y + w6 * c.z + w7 * c.w;
      }
    }
    float bi = bias[h];
    #pragma unroll
    for (int r = 0; r < 16; r++) out[(r0 + r) * 512u + h] = acc[r] + bi;
  }
}

// ---- kernel 2: recurrence, 4 WGs/batch, 512 thr; L2 fast exchange + IF$ fallback ----
__global__ __launch_bounds__(512, 1) void rnn_kernel(
    const int* __restrict__ lens, const float* __restrict__ Wa,
    const float* __restrict__ ba, const float* __restrict__ bs,
    const float* __restrict__ memb, char* __restrict__ ws,
    float* __restrict__ out)
{
  __shared__ __align__(16) uint4 wrsL[4096];      // 64 KB: Wrs quarter, [i][r][s] linear
  __shared__ __align__(16) float stk[2][4096];    // 32 KB stack dbuf (replicated)
  __shared__ __align__(16) __half waH[3072];      //  6 KB Wa fp16
  __shared__ __align__(16) __half hH[2][512];     //  2 KB hid dbuf, perm ph layout
  __shared__ __align__(16) __half tH[2][256];     //  1 KB tops dbuf, perm pt layout
  __shared__ __align__(16) float pvL[128];
  __shared__ __align__(16) float membL[128];
  __shared__ float bsL[128];
  __shared__ float lgts[8];
  __shared__ float baL[8];

  const uint32_t tid = threadIdx.x;
  const uint32_t wg = blockIdx.x;
  const uint32_t q = wg >> 6;      // quarter 0..3 (wg = q*64+b: all 4 q's share b%8 -> same XCD)
  const uint32_t b = wg & 63u;
  const int len = lens[b];
  const uint32_t r = tid >> 2, s = tid & 3u;   // row-in-quarter (0..127), K-slice (0..3)
  const uint32_t h = q * 128u + r;

  const uint4* whp  = (const uint4*)(ws + WHP_OFF);
  const uint4* wrsp = (const uint4*)(ws + WRSP_OFF);
  const uint4* wsp  = (const uint4*)(ws + WSP_OFF);
  uint32_t* Xf = (uint32_t*)(ws + X_OFF);
  uint32_t* Xs = (uint32_t*)(ws + XS_OFF);

  // ---- register-resident: Wh quarter 64 + Ws FULL 64 = 128 regs
  uint4 wh[16], wsr[16];
  #pragma unroll
  for (int i = 0; i < 16; i++) wh[i]  = whp[(s * 16u + (uint32_t)i) * 512u + h];
  #pragma unroll
  for (int j = 0; j < 16; j++) wsr[j] = wsp[(s * 16u + (uint32_t)j) * 128u + r];
  #pragma unroll
  for (int i = 0; i < 16; i++) KEEP4(wh[i]);
  #pragma unroll
  for (int i = 0; i < 16; i++) KEEP4(wsr[i]);

  // ---- Wrs quarter -> LDS, layout [i][r][s]: read index = i*512 + tid (lane-linear)
  #pragma unroll
  for (int i = 0; i < 8; i++) {
    wrsL[(uint32_t)i * 512u + r * 4u + s] =
        wrsp[(s * 8u + (uint32_t)i) * 512u + q * 128u + r];
  }

  for (uint32_t i = tid; i < 3072u; i += 512u) waH[i] = __float2half(Wa[i]);
  if (tid < 128u) { membL[tid] = memb[tid]; bsL[tid] = bs[tid]; }
  if (tid < 64u)  ((uint4*)hH[0])[tid] = uint4{0u, 0u, 0u, 0u};
  if (tid < 256u) {  // tops init = mem_bias, perm pt layout
    uint32_t jb = tid >> 3, e = tid & 7u, n = tid >> 7, d = tid & 63u;
    uint32_t pt = ((jb & 7u) << 2) | (jb >> 3);
    ((__half*)tH[0])[pt * 8u + e] = __float2half(memb[n * 64u + d]);
  }
  if (tid < 8u) baL[tid] = (tid < 6u) ? ba[tid] : 0.f;
  __syncthreads();
  {
    uint32_t c = tid * 4u, d = c & 63u;
    *(float4*)&stk[0][c]         = *(const float4*)&membL[d];
    *(float4*)&stk[0][2048u + c] = *(const float4*)&membL[64u + d];
  }
  float eCur = (s == 0) ? out[b * 512u + h] : 0.f;
  __syncthreads();

  for (int t = 0; t < kT; t++) {
    const int cur = t & 1, nxt = cur ^ 1;
    const bool lastT = (t == len - 1);
    const uint4* hc = (const uint4*)hH[cur];
    const uint4* tc = (const uint4*)tH[cur];

    float eNext = (s == 0 && t < kT - 1)
                ? out[((uint32_t)(t + 1) * 64u + b) * 512u + h] : 0.f;

    // ---- A1+A2 fused: mhid and push_vals share the hid fragments (transient regs)
    float acc0 = 0.f, acc1 = 0.f, wa0 = 0.f, wa1 = 0.f;
    #pragma unroll
    for (int i = 0; i < 8; i++) {
      uint4 ha = hc[(uint32_t)i * 4u + s];
      uint4 hb = hc[((uint32_t)i + 8u) * 4u + s];
      acc0 = dot8h(wh[i],      ha, acc0);
      acc1 = dot8h(wh[i + 8],  hb, acc1);
      wa0  = dot8h(wsr[i],     ha, wa0);
      wa1  = dot8h(wsr[i + 8], hb, wa1);
    }
    #pragma unroll
    for (int i = 0; i < 4; i++) {
      acc0 = dot8h(wrsL[(uint32_t)i * 512u + tid],        tc[(uint32_t)i * 4u + s], acc0);
      acc1 = dot8h(wrsL[((uint32_t)i + 4u) * 512u + tid], tc[((uint32_t)i + 4u) * 4u + s], acc1);
    }
    float acc = acc0 + acc1;
    acc += __shfl_xor(acc, 1, 64);
    acc += __shfl_xor(acc, 2, 64);
    if (s == 0) {
      float v = tanhf(acc + eCur);
      out[((uint32_t)t * 64u + b) * 512u + h] = v;
      if (lastT) out[OUT_HL + b * 512u + h] = v;
      __half vh = __float2half(v);
      uint32_t pay = ((uint32_t)(t + 1) << 16) | (uint32_t)__half_as_ushort(vh);
      uint32_t idx = (((uint32_t)cur * 64u + b) * 4u + q) * 128u + r;
      store_l2(&Xf[idx], pay);                                    // fast: same-XCD L2
      __hip_atomic_store(&Xs[idx], pay, __ATOMIC_RELAXED,
                         __HIP_MEMORY_SCOPE_AGENT);               // slow: guaranteed
      uint32_t kb = h >> 3, e = h & 7u;
      uint32_t ph = ((kb & 15u) << 2) | (kb >> 4);
      ((__half*)hH[nxt])[ph * 8u + e] = vh;   // own quarter, next buffer
    }
    eCur = eNext;

    float wa2 = wa0 + wa1;
    wa2 += __shfl_xor(wa2, 1, 64);
    wa2 += __shfl_xor(wa2, 2, 64);
    if (s == 0) pvL[r] = tanhf(wa2 + bsL[r]);

    // ---- A3: action logits (replicated)
    if (tid < 384u) {
      uint32_t o = tid >> 6, kb = tid & 63u;
      uint32_t ph = ((kb & 15u) << 2) | (kb >> 4);
      float la = dot8h(((const uint4*)waH)[o * 64u + kb], hc[ph], 0.f);
      #pragma unroll
      for (int off = 1; off <= 32; off <<= 1) la += __shfl_xor(la, off, 64);
      if (kb == 0) lgts[o] = la + baL[o];
    }
    __syncthreads();

    // ---- gather probe: issue first fast load; resolve after C
    uint32_t gx = 0, gidx = 0;
    const uint32_t want = (uint32_t)(t + 1) << 16;
    if (t < kT - 1 && tid < 384u) {
      uint32_t gj = tid >> 7;
      gj = gj + (gj >= q ? 1u : 0u);
      uint32_t gk = tid & 127u;
      gidx = (((uint32_t)cur * 64u + b) * 4u + gj) * 128u + gk;
      gx = load_l2(&Xf[gidx]);
    }

    // ---- C: stack blend, conflict-free (c = tid*4 per stack, n unrolled)
    {
      uint32_t c = tid * 4u;
      uint32_t sd = (c >> 6) & 31u, d = c & 63u;
      #pragma unroll
      for (int n = 0; n < 2; n++) {
        float l0 = lgts[n * 3], l1 = lgts[n * 3 + 1], l2 = lgts[n * 3 + 2];
        float m = fmaxf(l0, fmaxf(l1, l2));
        float e0 = __expf(l0 - m), e1 = __expf(l1 - m), e2 = __expf(l2 - m);
        float inv = 1.f / (e0 + e1 + e2);
        float p0 = e0 * inv, p1 = e1 * inv, p2 = e2 * inv;
        uint32_t cc = (uint32_t)n * 2048u + c;
        float4 scur = *(const float4*)&stk[cur][cc];
        float4 sp = (sd == 0) ? *(const float4*)&pvL[n * 64u + d]
                              : *(const float4*)&stk[cur][cc - 64u];
        float4 so = (sd == 31u) ? *(const float4*)&membL[n * 64u + d]
                                : *(const float4*)&stk[cur][cc + 64u];
        float4 nv;
        nv.x = p0 * sp.x + p1 * so.x + p2 * scur.x;
        nv.y = p0 * sp.y + p1 * so.y + p2 * scur.y;
        nv.z = p0 * sp.z + p1 * so.z + p2 * scur.z;
        nv.w = p0 * sp.w + p1 * so.w + p2 * scur.w;
        *(float4*)&stk[nxt][cc] = nv;
        if (sd < 2u) {  // new tops -> perm pt layout (next buffer)
          uint32_t f = (uint32_t)n * 128u + sd * 64u + d;
          uint32_t jb = f >> 3, e = f & 7u;
          uint32_t pt = ((jb & 7u) << 2) | (jb >> 3);
          uint32_t lo = ((uint32_t)__half_as_ushort(__float2half(nv.y)) << 16) |
                        __half_as_ushort(__float2half(nv.x));
          uint32_t hi = ((uint32_t)__half_as_ushort(__float2half(nv.w)) << 16) |
                        __half_as_ushort(__float2half(nv.z));
          *(uint2*)((__half*)tH[nxt] + pt * 8u + e) = uint2{lo, hi};
        }
        if (lastT && q == 0u) *(float4*)&out[OUT_SR + b * 4096u + cc] = nv;
      }
    }

    // ---- gather resolve: bounded fast poll (L2), then guaranteed slow poll (IF$)
    if (t < kT - 1 && tid < 384u) {
      uint32_t g = 0;
      while ((gx & 0xffff0000u) != want && g < 2048u) {
        gx = load_l2(&Xf[gidx]);
        ++g;
      }
      if ((gx & 0xffff0000u) != want) {
        g = 0;
        do {
          gx = __hip_atomic_load(&Xs[gidx], __ATOMIC_RELAXED, __HIP_MEMORY_SCOPE_AGENT);
        } while ((gx & 0xffff0000u) != want && ++g < (1u << 24));
      }
      uint32_t kb = gidx & 511u;       // gj*128 + gk = idx within this batch's 512 rows
      uint32_t e = kb & 7u; kb >>= 3;
      uint32_t ph = ((kb & 15u) << 2) | (kb >> 4);
      ((__half*)hH[nxt])[ph * 8u + e] = __ushort_as_half((unsigned short)(gx & 0xffffu));
    }
    __syncthreads();
  }
}

extern "C" void kernel_launch(void* const* d_in, const int* in_sizes, int n_in,
                              void* d_out, int out_size, void* d_ws, size_t ws_size,
                              hipStream_t stream) {
  const float* embs = (const float*)d_in[0];
  const int*   lens = (const int*)d_in[1];
  const float* We   = (const float*)d_in[2];
  const float* be   = (const float*)d_in[3];
  const float* Wh   = (const float*)d_in[4];
  const float* bh   = (const float*)d_in[5];
  const float* Wa   = (const float*)d_in[6];
  const float* ba   = (const float*)d_in[7];
  const float* Ws   = (const float*)d_in[8];
  const float* bs   = (const float*)d_in[9];
  const float* Wr   = (const float*)d_in[10];
  const float* br   = (const float*)d_in[11];
  const float* memb = (const float*)d_in[12];
  float* out = (float*)d_out;
  char* ws = (char*)d_ws;

  pack_kernel<<<1024, 256, 0, stream>>>(Wh, Wr, Ws, We, be, bh, br, ws);
  embed_kernel<<<2048, 256, 0, stream>>>(embs, ws, out);
  rnn_kernel<<<256, 512, 0, stream>>>(lens, Wa, ba, bs, memb, ws, out);
}

// Round 12
// 1277.915 us; speedup vs baseline: 77.4038x; 77.4038x over previous
//
#include <hip/hip_runtime.h>
#include <hip/hip_bf16.h>
#include <hip/hip_fp16.h>
#include <stdint.h>

constexpr int kT = 512;

// d_ws byte offsets
constexpr uint32_t WHP_OFF  = 0u;        // [64][512][8] fp16 : Wh[h][kb*8+e]
constexpr uint32_t WRSP_OFF = 524288u;   // [32][512][8] fp16 : Wr+Wr' summed
constexpr uint32_t WSP_OFF  = 786432u;   // [64][128][8] fp16 : Ws[o][kb*8+e]
constexpr uint32_t WEP_OFF  = 917504u;   // [32][512][8] bf16 : We[h][kb*8+e]
constexpr uint32_t BIAS_OFF = 1179648u;  // [512] f32
constexpr uint32_t X_OFF    = 1181696u;  // [2][64][4][128] u32 tag|fp16 exchange

// d_out element offsets (fp32)
constexpr uint32_t OUT_HL = 16777216u;
constexpr uint32_t OUT_SR = 16809984u;

static __device__ __forceinline__ float bitsf(uint32_t u) {
  union { uint32_t u; float f; } c; c.u = u; return c.f;
}

typedef _Float16 h2_t __attribute__((ext_vector_type(2)));

static __device__ __forceinline__ float dot2acc(uint32_t w, uint32_t h, float acc) {
#if __has_builtin(__builtin_amdgcn_fdot2)
  return __builtin_amdgcn_fdot2(__builtin_bit_cast(h2_t, w),
                                __builtin_bit_cast(h2_t, h), acc, false);
#else
  h2_t wv = __builtin_bit_cast(h2_t, w), hv = __builtin_bit_cast(h2_t, h);
  return acc + (float)wv.x * (float)hv.x + (float)wv.y * (float)hv.y;
#endif
}

static __device__ __forceinline__ float dot8h(uint4 w, uint4 h, float acc) {
  acc = dot2acc(w.x, h.x, acc);
  acc = dot2acc(w.y, h.y, acc);
  acc = dot2acc(w.z, h.z, acc);
  acc = dot2acc(w.w, h.w, acc);
  return acc;
}

// opaque keep-alive: blocks load rematerialization of register-resident weights
#define KEEP4(v) asm volatile("" : "+v"((v).x), "+v"((v).y), "+v"((v).z), "+v"((v).w))

// ---------------- kernel 0: pack weights + fold biases ----------------
__global__ __launch_bounds__(256) void pack_kernel(
    const float* __restrict__ Wh, const float* __restrict__ Wr,
    const float* __restrict__ Ws, const float* __restrict__ We,
    const float* __restrict__ be, const float* __restrict__ bh,
    const float* __restrict__ br, char* __restrict__ ws)
{
  uint32_t g = blockIdx.x * 256u + threadIdx.x;
  __half* whp  = (__half*)(ws + WHP_OFF);
  __half* wrsp = (__half*)(ws + WRSP_OFF);
  __half* wsp  = (__half*)(ws + WSP_OFF);
  __hip_bfloat16* wep = (__hip_bfloat16*)(ws + WEP_OFF);
  float* bias = (float*)(ws + BIAS_OFF);

  if (g < 262144u) {
    uint32_t e = g & 7u, h = (g >> 3) & 511u, kb = g >> 12;
    whp[g] = __float2half(Wh[h * 512u + kb * 8u + e]);
  }
  if (g < 131072u) {
    uint32_t e = g & 7u, h = (g >> 3) & 511u, jb = g >> 12;
    wrsp[g] = __float2half(Wr[h * 256u + jb * 8u + e] +
                           Wr[(512u + h) * 256u + jb * 8u + e]);
  }
  if (g < 65536u) {
    uint32_t e = g & 7u, o = (g >> 3) & 127u, kb = g >> 10;
    wsp[g] = __float2half(Ws[o * 512u + kb * 8u + e]);
  }
  if (g < 131072u) {
    uint32_t e = g & 7u, h = (g >> 3) & 511u, kb = g >> 12;
    wep[g] = __float2bfloat16(We[h * 256u + kb * 8u + e]);
  }
  if (g < 512u) bias[g] = be[g] + bh[g] + br[g] + br[512u + g];
}

// ---------------- kernel 1: E = emb @ We.T + biases -> d_out output region --------
__global__ __launch_bounds__(256) void embed_kernel(
    const float* __restrict__ embs, const char* __restrict__ ws,
    float* __restrict__ out)
{
  __shared__ __align__(16) float embL[16 * 256];
  const uint32_t tid = threadIdx.x;
  const uint32_t r0 = blockIdx.x * 16u;
  #pragma unroll
  for (int i = 0; i < 16; i++) embL[tid + i * 256] = embs[r0 * 256u + tid + i * 256u];
  __syncthreads();

  const uint4* wep = (const uint4*)(ws + WEP_OFF);
  const float* bias = (const float*)(ws + BIAS_OFF);

  for (int hb = 0; hb < 2; hb++) {
    uint32_t h = hb * 256u + tid;
    float acc[16];
    #pragma unroll
    for (int r = 0; r < 16; r++) acc[r] = 0.f;
    for (int kb = 0; kb < 32; kb++) {
      uint4 v = wep[kb * 512u + h];
      float w0 = bitsf(v.x << 16), w1 = bitsf(v.x & 0xffff0000u);
      float w2 = bitsf(v.y << 16), w3 = bitsf(v.y & 0xffff0000u);
      float w4 = bitsf(v.z << 16), w5 = bitsf(v.z & 0xffff0000u);
      float w6 = bitsf(v.w << 16), w7 = bitsf(v.w & 0xffff0000u);
      #pragma unroll
      for (int r = 0; r < 16; r++) {
        const float4* e4 = (const float4*)&embL[r * 256 + kb * 8];
        float4 a = e4[0], c = e4[1];
        acc[r] += w0 * a.x + w1 * a.y + w2 * a.z + w3 * a.w
                + w4 * c.x + w5 * c.y + w6 * c.z + w7 * c.w;
      }
    }
    float bi = bias[h];
    #pragma unroll
    for (int r = 0; r < 16; r++) out[(r0 + r) * 512u + h] = acc[r] + bi;
  }
}

// ---- kernel 2: recurrence, 4 WGs/batch, 512 thr; agent-scope tag-in-data exchange ----
__global__ __launch_bounds__(512, 1) void rnn_kernel(
    const int* __restrict__ lens, const float* __restrict__ Wa,
    const float* __restrict__ ba, const float* __restrict__ bs,
    const float* __restrict__ memb, char* __restrict__ ws,
    float* __restrict__ out)
{
  __shared__ __align__(16) uint4 wrsL[4096];      // 64 KB: Wrs quarter, [i][r][s] linear
  __shared__ __align__(16) float stk[2][4096];    // 32 KB stack dbuf (replicated)
  __shared__ __align__(16) __half waH[3072];      //  6 KB Wa fp16
  __shared__ __align__(16) __half hH[2][512];     //  2 KB hid dbuf, perm ph layout
  __shared__ __align__(16) __half tH[2][256];     //  1 KB tops dbuf, perm pt layout
  __shared__ __align__(16) float pvL[128];
  __shared__ __align__(16) float membL[128];
  __shared__ float bsL[128];
  __shared__ float lgts[8];
  __shared__ float baL[8];

  const uint32_t tid = threadIdx.x;
  const uint32_t wg = blockIdx.x;
  const uint32_t q = wg >> 6;      // quarter 0..3 (wg = q*64+b)
  const uint32_t b = wg & 63u;
  const int len = lens[b];
  const uint32_t r = tid >> 2, s = tid & 3u;   // row-in-quarter (0..127), K-slice (0..3)
  const uint32_t h = q * 128u + r;

  const uint4* whp  = (const uint4*)(ws + WHP_OFF);
  const uint4* wrsp = (const uint4*)(ws + WRSP_OFF);
  const uint4* wsp  = (const uint4*)(ws + WSP_OFF);
  uint32_t* X32 = (uint32_t*)(ws + X_OFF);

  // ---- register-resident: Wh quarter 64 + Ws FULL 64 = 128 regs
  uint4 wh[16], wsr[16];
  #pragma unroll
  for (int i = 0; i < 16; i++) wh[i]  = whp[(s * 16u + (uint32_t)i) * 512u + h];
  #pragma unroll
  for (int j = 0; j < 16; j++) wsr[j] = wsp[(s * 16u + (uint32_t)j) * 128u + r];
  #pragma unroll
  for (int i = 0; i < 16; i++) KEEP4(wh[i]);
  #pragma unroll
  for (int i = 0; i < 16; i++) KEEP4(wsr[i]);

  // ---- Wrs quarter -> LDS, layout [i][r][s]: read index = i*512 + tid (lane-linear)
  #pragma unroll
  for (int i = 0; i < 8; i++) {
    wrsL[(uint32_t)i * 512u + r * 4u + s] =
        wrsp[(s * 8u + (uint32_t)i) * 512u + q * 128u + r];
  }

  for (uint32_t i = tid; i < 3072u; i += 512u) waH[i] = __float2half(Wa[i]);
  if (tid < 128u) { membL[tid] = memb[tid]; bsL[tid] = bs[tid]; }
  if (tid < 64u)  ((uint4*)hH[0])[tid] = uint4{0u, 0u, 0u, 0u};
  if (tid < 256u) {  // tops init = mem_bias, perm pt layout
    uint32_t jb = tid >> 3, e = tid & 7u, n = tid >> 7, d = tid & 63u;
    uint32_t pt = ((jb & 7u) << 2) | (jb >> 3);
    ((__half*)tH[0])[pt * 8u + e] = __float2half(memb[n * 64u + d]);
  }
  if (tid < 8u) baL[tid] = (tid < 6u) ? ba[tid] : 0.f;
  __syncthreads();
  {
    uint32_t c = tid * 4u, d = c & 63u;
    *(float4*)&stk[0][c]         = *(const float4*)&membL[d];
    *(float4*)&stk[0][2048u + c] = *(const float4*)&membL[64u + d];
  }
  float eCur = (s == 0) ? out[b * 512u + h] : 0.f;
  __syncthreads();

  for (int t = 0; t < kT; t++) {
    const int cur = t & 1, nxt = cur ^ 1;
    const bool lastT = (t == len - 1);
    const uint4* hc = (const uint4*)hH[cur];
    const uint4* tc = (const uint4*)tH[cur];

    float eNext = (s == 0 && t < kT - 1)
                ? out[((uint32_t)(t + 1) * 64u + b) * 512u + h] : 0.f;

    // ---- A1+A2 fused: mhid and push_vals share the hid fragments (transient regs)
    float acc0 = 0.f, acc1 = 0.f, wa0 = 0.f, wa1 = 0.f;
    #pragma unroll
    for (int i = 0; i < 8; i++) {
      uint4 ha = hc[(uint32_t)i * 4u + s];
      uint4 hb = hc[((uint32_t)i + 8u) * 4u + s];
      acc0 = dot8h(wh[i],      ha, acc0);
      acc1 = dot8h(wh[i + 8],  hb, acc1);
      wa0  = dot8h(wsr[i],     ha, wa0);
      wa1  = dot8h(wsr[i + 8], hb, wa1);
    }
    #pragma unroll
    for (int i = 0; i < 4; i++) {
      acc0 = dot8h(wrsL[(uint32_t)i * 512u + tid],        tc[(uint32_t)i * 4u + s], acc0);
      acc1 = dot8h(wrsL[((uint32_t)i + 4u) * 512u + tid], tc[((uint32_t)i + 4u) * 4u + s], acc1);
    }
    float acc = acc0 + acc1;
    acc += __shfl_xor(acc, 1, 64);
    acc += __shfl_xor(acc, 2, 64);
    if (s == 0) {
      float v = tanhf(acc + eCur);
      out[((uint32_t)t * 64u + b) * 512u + h] = v;
      if (lastT) out[OUT_HL + b * 512u + h] = v;
      __half vh = __float2half(v);
      uint32_t pay = ((uint32_t)(t + 1) << 16) | (uint32_t)__half_as_ushort(vh);
      __hip_atomic_store(&X32[(((uint32_t)cur * 64u + b) * 4u + q) * 128u + r], pay,
                         __ATOMIC_RELAXED, __HIP_MEMORY_SCOPE_AGENT);
      uint32_t kb = h >> 3, e = h & 7u;
      uint32_t ph = ((kb & 15u) << 2) | (kb >> 4);
      ((__half*)hH[nxt])[ph * 8u + e] = vh;   // own quarter, next buffer
    }
    eCur = eNext;

    float wa2 = wa0 + wa1;
    wa2 += __shfl_xor(wa2, 1, 64);
    wa2 += __shfl_xor(wa2, 2, 64);
    if (s == 0) pvL[r] = tanhf(wa2 + bsL[r]);

    // ---- A3: action logits (replicated)
    if (tid < 384u) {
      uint32_t o = tid >> 6, kb = tid & 63u;
      uint32_t ph = ((kb & 15u) << 2) | (kb >> 4);
      float la = dot8h(((const uint4*)waH)[o * 64u + kb], hc[ph], 0.f);
      #pragma unroll
      for (int off = 1; off <= 32; off <<= 1) la += __shfl_xor(la, off, 64);
      if (kb == 0) lgts[o] = la + baL[o];
    }
    __syncthreads();

    // ---- gather probe: issue first foreign-quarter load; resolve after C
    uint32_t gx = 0, gidx = 0;
    uint32_t* gsrc = nullptr;
    const uint32_t want = (uint32_t)(t + 1) << 16;
    if (t < kT - 1 && tid < 384u) {
      uint32_t gj = tid >> 7;
      gj = gj + (gj >= q ? 1u : 0u);
      uint32_t gk = tid & 127u;
      gidx = (((uint32_t)cur * 64u + b) * 4u + gj) * 128u + gk;
      gsrc = &X32[gidx];
      gx = __hip_atomic_load(gsrc, __ATOMIC_RELAXED, __HIP_MEMORY_SCOPE_AGENT);
    }

    // ---- C: stack blend, conflict-free (c = tid*4 per stack, n unrolled)
    {
      uint32_t c = tid * 4u;
      uint32_t sd = (c >> 6) & 31u, d = c & 63u;
      #pragma unroll
      for (int n = 0; n < 2; n++) {
        float l0 = lgts[n * 3], l1 = lgts[n * 3 + 1], l2 = lgts[n * 3 + 2];
        float m = fmaxf(l0, fmaxf(l1, l2));
        float e0 = __expf(l0 - m), e1 = __expf(l1 - m), e2 = __expf(l2 - m);
        float inv = 1.f / (e0 + e1 + e2);
        float p0 = e0 * inv, p1 = e1 * inv, p2 = e2 * inv;
        uint32_t cc = (uint32_t)n * 2048u + c;
        float4 scur = *(const float4*)&stk[cur][cc];
        float4 sp = (sd == 0) ? *(const float4*)&pvL[n * 64u + d]
                              : *(const float4*)&stk[cur][cc - 64u];
        float4 so = (sd == 31u) ? *(const float4*)&membL[n * 64u + d]
                                : *(const float4*)&stk[cur][cc + 64u];
        float4 nv;
        nv.x = p0 * sp.x + p1 * so.x + p2 * scur.x;
        nv.y = p0 * sp.y + p1 * so.y + p2 * scur.y;
        nv.z = p0 * sp.z + p1 * so.z + p2 * scur.z;
        nv.w = p0 * sp.w + p1 * so.w + p2 * scur.w;
        *(float4*)&stk[nxt][cc] = nv;
        if (sd < 2u) {  // new tops -> perm pt layout (next buffer)
          uint32_t f = (uint32_t)n * 128u + sd * 64u + d;
          uint32_t jb = f >> 3, e = f & 7u;
          uint32_t pt = ((jb & 7u) << 2) | (jb >> 3);
          uint32_t lo = ((uint32_t)__half_as_ushort(__float2half(nv.y)) << 16) |
                        __half_as_ushort(__float2half(nv.x));
          uint32_t hi = ((uint32_t)__half_as_ushort(__float2half(nv.w)) << 16) |
                        __half_as_ushort(__float2half(nv.z));
          *(uint2*)((__half*)tH[nxt] + pt * 8u + e) = uint2{lo, hi};
        }
        if (lastT && q == 0u) *(float4*)&out[OUT_SR + b * 4096u + cc] = nv;
      }
    }

    // ---- gather resolve: poll until tag matches (first latency hidden under C)
    if (t < kT - 1 && tid < 384u) {
      uint32_t g = 0;
      while ((gx & 0xffff0000u) != want) {
        gx = __hip_atomic_load(gsrc, __ATOMIC_RELAXED, __HIP_MEMORY_SCOPE_AGENT);
        if (++g > (1u << 24)) break;   // bounded: no hang even if model wrong
      }
      uint32_t kb = gidx & 511u;       // index within this batch's 512 rows
      uint32_t e = kb & 7u; kb >>= 3;
      uint32_t ph = ((kb & 15u) << 2) | (kb >> 4);
      ((__half*)hH[nxt])[ph * 8u + e] = __ushort_as_half((unsigned short)(gx & 0xffffu));
    }
    __syncthreads();
  }
}

extern "C" void kernel_launch(void* const* d_in, const int* in_sizes, int n_in,
                              void* d_out, int out_size, void* d_ws, size_t ws_size,
                              hipStream_t stream) {
  const float* embs = (const float*)d_in[0];
  const int*   lens = (const int*)d_in[1];
  const float* We   = (const float*)d_in[2];
  const float* be   = (const float*)d_in[3];
  const float* Wh   = (const float*)d_in[4];
  const float* bh   = (const float*)d_in[5];
  const float* Wa   = (const float*)d_in[6];
  const float* ba   = (const float*)d_in[7];
  const float* Ws   = (const float*)d_in[8];
  const float* bs   = (const float*)d_in[9];
  const float* Wr   = (const float*)d_in[10];
  const float* br   = (const float*)d_in[11];
  const float* memb = (const float*)d_in[12];
  float* out = (float*)d_out;
  char* ws = (char*)d_ws;

  pack_kernel<<<1024, 256, 0, stream>>>(Wh, Wr, Ws, We, be, bh, br, ws);
  embed_kernel<<<2048, 256, 0, stream>>>(embs, ws, out);
  rnn_kernel<<<256, 512, 0, stream>>>(lens, Wa, ba, bs, memb, ws, out);
}